// Round 4
// baseline (230.594 us; speedup 1.0000x reference)
//
#include <hip/hip_runtime.h>

#define B_ 256
#define T_ 512
#define C_ 256
#define L_ 64
#define S_ 129
#define TCH 64      // timesteps per pipelined chunk (T_/TCH = 8 chunks)
#define NEG -1e30f
#define LOG2E 1.44269504f
#define LN2 0.69314718f

__device__ __forceinline__ unsigned short f2h(float f) {
    _Float16 h = (_Float16)f;           // round-to-nearest-even
    return __builtin_bit_cast(unsigned short, h);
}
__device__ __forceinline__ float h2f(unsigned short u) {
    return (float)__builtin_bit_cast(_Float16, u);
}

// lane l gets x from lane l-1 (wave_shr1 DPP 0x138); lane 0 gets `fill`.
__device__ __forceinline__ float shr1(float x, float fill) {
    int r = __builtin_amdgcn_update_dpp(__builtin_bit_cast(int, fill),
                                        __builtin_bit_cast(int, x),
                                        0x138, 0xF, 0xF, false);
    return __builtin_bit_cast(float, r);
}

// Canonical GCN wave64 sum-reduce on the VALU (no LDS pipe):
// row_shr 1/2/4/8 + row_bcast15/31, total lands in lane 63.
__device__ __forceinline__ float wave_sum(float x) {
#define DPPADD(ctrl)                                                          \
    {                                                                         \
        int _t = __builtin_amdgcn_update_dpp(0, __builtin_bit_cast(int, x),   \
                                             (ctrl), 0xF, 0xF, true);         \
        x += __builtin_bit_cast(float, _t);                                   \
    }
    DPPADD(0x111)  // row_shr:1
    DPPADD(0x112)  // row_shr:2
    DPPADD(0x114)  // row_shr:4
    DPPADD(0x118)  // row_shr:8
    DPPADD(0x142)  // row_bcast:15
    DPPADD(0x143)  // row_bcast:31
#undef DPPADD
    return __builtin_bit_cast(float,
        __builtin_amdgcn_readlane(__builtin_bit_cast(int, x), 63));
}

// One CTC alpha step, log2 domain. Lane l owns states 2l (a0), 2l+1 (a1);
// lane 63 also owns state 128 (a2). q packs (lp_blank, lp_odd) as 2x fp16.
__device__ __forceinline__ void ctc_step(float& a0, float& a1, float& a2,
                                         unsigned int q, bool skip) {
    const float lpb = h2f((unsigned short)(q & 0xffffu));
    const float lpo = h2f((unsigned short)(q >> 16));
    const float p = shr1(a1, NEG);                       // a1 from lane l-1
    const float m0 = fmaxf(a0, p), n0 = fminf(a0, p);
    const float a0n = m0 + __log2f(1.0f + exp2f(n0 - m0)) + lpb;
    const float c  = skip ? p : NEG;
    const float m1 = fmaxf(fmaxf(a1, a0), c);
    const float s1 = exp2f(a1 - m1) + exp2f(a0 - m1) + exp2f(c - m1);
    const float a1n = m1 + __log2f(s1) + lpo;
    const float m2 = fmaxf(a2, a1), n2 = fminf(a2, a1);
    const float a2n = m2 + __log2f(1.0f + exp2f(n2 - m2)) + lpb;
    a0 = a0n; a1 = a1n; a2 = a2n;
}

// ---------------------------------------------------------------------------
// Fused kernel: one block per batch row, 9 waves.
// Waves 1..8: log2-softmax + label gather for chunk k -> LDS Gs[k&1].
//             (phase-split loads for MLP; DPP reduction keeps LDS pipe free)
// Wave 0:     alpha recurrence over chunk k-1, rolling 8-reg LDS window.
// ---------------------------------------------------------------------------
__global__ __launch_bounds__(576) void k_fused(const float* __restrict__ logits,
                                               const int* __restrict__ targets,
                                               const int* __restrict__ in_len,
                                               const int* __restrict__ tg_len,
                                               float* __restrict__ out) {
    const int b = blockIdx.x;
    const int w = threadIdx.x >> 6;      // 0..8
    const int l = threadIdx.x & 63;

    __shared__ unsigned int Gs[2][TCH][64];   // 32 KB
    __shared__ int   tgt_sh[L_];
    __shared__ float alpha_sh[S_];

    if (threadIdx.x < L_) tgt_sh[threadIdx.x] = targets[(b << 6) + threadIdx.x];
    __syncthreads();

    const int len = in_len[b];
    float a0 = NEG, a1 = NEG, a2 = NEG;
    bool skip = false;
    if (w == 0) {
        const int tc = tgt_sh[l];
        const int tp = __shfl_up(tc, 1);
        skip = (l >= 1) && (tc != tp);
        __builtin_amdgcn_s_setprio(1);   // consumer wave owns the serial chain
    }
    const int mytgt = tgt_sh[l];

    const size_t rowbase = (size_t)b * T_;

    for (int k = 0; k < 9; ++k) {
        if (w > 0 && k < 8) {
            const int tt0 = (w - 1) * 8;
            // phase 1: issue all 16 loads (8 rows + 8 gathers) back-to-back
            float4 v[8];
            float  lv[8];
            #pragma unroll
            for (int r = 0; r < 8; ++r) {
                const int t = k * TCH + tt0 + r;
                v[r]  = ((const float4*)logits)[(rowbase + t) * 64 + l];
                lv[r] = logits[(rowbase + t) * C_ + mytgt];
            }
            // phase 2: compute
            #pragma unroll
            for (int r = 0; r < 8; ++r) {
                const int tt = tt0 + r;
                const float yx = v[r].x * LOG2E, yy = v[r].y * LOG2E;
                const float yz = v[r].z * LOG2E, yw = v[r].w * LOG2E;
                float s = exp2f(yx) + exp2f(yy) + exp2f(yz) + exp2f(yw);
                const float stot = wave_sum(s);
                const float lse2 = __log2f(stot);
                const float lpb  = __builtin_bit_cast(float,
                    __builtin_amdgcn_readfirstlane(__builtin_bit_cast(int, yx))) - lse2;
                const float lpo  = lv[r] * LOG2E - lse2;
                Gs[k & 1][tt][l] = (unsigned int)f2h(lpb)
                                 | ((unsigned int)f2h(lpo) << 16);
            }
        }
        if (w == 0 && k >= 1) {
            const int kb = (k - 1) & 1;
            const int base = (k - 1) * TCH;
            unsigned int qa[8], qb[8];
            #pragma unroll
            for (int j = 0; j < 8; ++j) qa[j] = Gs[kb][j][l];
            if (base == 0) {
                a0 = (l == 0) ? h2f((unsigned short)(qa[0] & 0xffffu)) : NEG;
                a1 = (l == 0) ? h2f((unsigned short)(qa[0] >> 16))     : NEG;
                a2 = NEG;
            }
            for (int g = 0; g < 8; ++g) {
                if (g < 7) {
                    #pragma unroll
                    for (int j = 0; j < 8; ++j)
                        qb[j] = Gs[kb][(g + 1) * 8 + j][l];
                }
                #pragma unroll
                for (int j = 0; j < 8; ++j) {
                    const int t = base + g * 8 + j;
                    if (t >= 1 && t < len)       // wave-uniform guard
                        ctc_step(a0, a1, a2, qa[j], skip);
                }
                if (g < 7) {
                    #pragma unroll
                    for (int j = 0; j < 8; ++j) qa[j] = qb[j];
                }
            }
        }
        __syncthreads();
    }

    if (w == 0) {
        alpha_sh[2 * l]     = a0;
        alpha_sh[2 * l + 1] = a1;
        if (l == 63) alpha_sh[128] = a2;
    }
    __syncthreads();
    if (threadIdx.x == 0) {
        const int tl = tg_len[b];
        const float al = alpha_sh[2 * tl];
        const float ap = alpha_sh[2 * tl - 1];
        const float m  = fmaxf(al, ap);
        float loss = -LN2 * (m + __log2f(exp2f(al - m) + exp2f(ap - m)));
        if (loss > 1e20f) loss = 0.0f;           // zero_infinity
        atomicAdd(out, loss / (float)tl * (1.0f / (float)B_));
    }
}

extern "C" void kernel_launch(void* const* d_in, const int* in_sizes, int n_in,
                              void* d_out, int out_size, void* d_ws, size_t ws_size,
                              hipStream_t stream) {
    const float* logits  = (const float*)d_in[0];
    const int*   targets = (const int*)d_in[1];
    const int*   in_len  = (const int*)d_in[2];
    const int*   tg_len  = (const int*)d_in[3];
    float*       out     = (float*)d_out;

    hipMemsetAsync(d_out, 0, sizeof(float), stream);
    k_fused<<<B_, 576, 0, stream>>>(logits, targets, in_len, tg_len, out);
}

// Round 7
// 204.209 us; speedup vs baseline: 1.1292x; 1.1292x over previous
//
#include <hip/hip_runtime.h>

#define B_ 256
#define T_ 512
#define C_ 256
#define L_ 64
#define S_ 129
#define TCH 64      // timesteps per pipelined chunk (T_/TCH = 8 chunks)
#define LOG2E 1.44269504f
#define LN2 0.69314718f

template <int CTRL>
__device__ __forceinline__ int dpp_mov_i32(int x) {
    return __builtin_amdgcn_update_dpp(0, x, CTRL, 0xF, 0xF, true);
}

// f64 whole-wave shift-right-by-1 (lane l <- lane l-1; lane 0 <- +0.0).
__device__ __forceinline__ double shr1d(double x) {
    int2 u = __builtin_bit_cast(int2, x);
    u.x = dpp_mov_i32<0x138>(u.x);
    u.y = dpp_mov_i32<0x138>(u.y);
    return __builtin_bit_cast(double, u);
}

template <int CTRL>
__device__ __forceinline__ double dpp_mov_f64(double x) {
    int2 u = __builtin_bit_cast(int2, x);
    u.x = dpp_mov_i32<CTRL>(u.x);
    u.y = dpp_mov_i32<CTRL>(u.y);
    return __builtin_bit_cast(double, u);
}

// wave64 f32 sum on the VALU; total lands in lane 63, broadcast via readlane.
__device__ __forceinline__ float wave_sum(float x) {
#define DPPADD(ctrl)                                                          \
    x += __builtin_bit_cast(float, dpp_mov_i32<ctrl>(__builtin_bit_cast(int, x)));
    DPPADD(0x111) DPPADD(0x112) DPPADD(0x114)
    DPPADD(0x118) DPPADD(0x142) DPPADD(0x143)
#undef DPPADD
    return __builtin_bit_cast(float,
        __builtin_amdgcn_readlane(__builtin_bit_cast(int, x), 63));
}

// wave64 max of nonneg doubles, broadcast to all lanes.
__device__ __forceinline__ double wave_max_d(double x) {
    x = fmax(x, dpp_mov_f64<0x111>(x));
    x = fmax(x, dpp_mov_f64<0x112>(x));
    x = fmax(x, dpp_mov_f64<0x114>(x));
    x = fmax(x, dpp_mov_f64<0x118>(x));
    x = fmax(x, dpp_mov_f64<0x142>(x));
    x = fmax(x, dpp_mov_f64<0x143>(x));
    int2 u = __builtin_bit_cast(int2, x);
    u.x = __builtin_amdgcn_readlane(u.x, 63);
    u.y = __builtin_amdgcn_readlane(u.y, 63);
    return __builtin_bit_cast(double, u);
}

// Exact wave-wide power-of-2 rescale; accumulated exponent in e.
__device__ __forceinline__ void rescale(double& a0, double& a1, double& a2, int& e) {
    const double m = wave_max_d(fmax(fmax(a0, a1), a2));
    const int hi = __builtin_bit_cast(int2, m).y;
    int ex = ((hi >> 20) & 0x7ff) - 1023;
    if (m == 0.0) ex = 0;                 // safety (state 0 is always > 0)
    e += ex;
    int2 fb; fb.x = 0; fb.y = (1023 - ex) << 20;
    const double f = __builtin_bit_cast(double, fb);  // exact 2^-ex
    a0 *= f; a1 *= f; a2 *= f;
}

// log2 of a positive double as float: exponent + log2(mantissa).
__device__ __forceinline__ float log2_pos(double a) {
    if (a == 0.0) return -1e30f;
    int2 u = __builtin_bit_cast(int2, a);
    const int ex = ((u.y >> 20) & 0x7ff) - 1023;
    u.y = (u.y & 0x800FFFFF) | (1023 << 20);          // mantissa in [1,2)
    const float mf = (float)__builtin_bit_cast(double, u);
    return __log2f(mf) + (float)ex;
}

// ---------------------------------------------------------------------------
// Fused kernel: one block per batch row, 9 waves.
// Waves 1..8: softmax (prob domain, fp32) + label gather -> LDS.
// Wave 0:     alpha recurrence in fp64 prob domain — per step only
//             shr1 + cndmask + add + mul on the serial chain (no
//             transcendentals); exact wave-wide 2^-e rescale every 32 steps.
// ---------------------------------------------------------------------------
__global__ __launch_bounds__(576) void k_fused(const float* __restrict__ logits,
                                               const int* __restrict__ targets,
                                               const int* __restrict__ in_len,
                                               const int* __restrict__ tg_len,
                                               float* __restrict__ out) {
    const int b = blockIdx.x;
    const int w = threadIdx.x >> 6;      // 0..8
    const int l = threadIdx.x & 63;

    __shared__ float Pb[2][TCH][64];     // blank prob per (t, lane)  32 KB
    __shared__ float Po[2][TCH][64];     // odd-label prob            32 KB
    __shared__ int   tgt_sh[L_];
    __shared__ float alpha_sh[S_];

    if (threadIdx.x < L_) tgt_sh[threadIdx.x] = targets[(b << 6) + threadIdx.x];
    __syncthreads();

    const int len = in_len[b];
    double a0 = 0.0, a1 = 0.0, a2 = 0.0;
    int scale_total = 0;                 // wave-uniform (wave 0)
    bool skip = false;
    if (w == 0) {
        const int tc = tgt_sh[l];
        const int tp = __shfl_up(tc, 1);
        skip = (l >= 1) && (tc != tp);
        __builtin_amdgcn_s_setprio(1);   // consumer owns the serial chain
    }
    const int mytgt = tgt_sh[l];

    const size_t rowbase = (size_t)b * T_;

    for (int k = 0; k < 9; ++k) {
        if (w > 0 && k < 8) {
            const int tt0 = (w - 1) * 8;
            float4 v[8];
            float  lv[8];
            #pragma unroll
            for (int r = 0; r < 8; ++r) {
                const int t = k * TCH + tt0 + r;
                v[r]  = ((const float4*)logits)[(rowbase + t) * 64 + l];
                lv[r] = logits[(rowbase + t) * C_ + mytgt];
            }
            #pragma unroll
            for (int r = 0; r < 8; ++r) {
                const int tt = tt0 + r;
                const float e0 = exp2f(v[r].x * LOG2E);
                const float e1 = exp2f(v[r].y * LOG2E);
                const float e2 = exp2f(v[r].z * LOG2E);
                const float e3 = exp2f(v[r].w * LOG2E);
                const float stot = wave_sum(e0 + e1 + e2 + e3);
                const float rs = __builtin_amdgcn_rcpf(stot);
                const float eb = __builtin_bit_cast(float,
                    __builtin_amdgcn_readfirstlane(__builtin_bit_cast(int, e0)));
                Pb[k & 1][tt][l] = eb * rs;                       // p(blank)
                Po[k & 1][tt][l] = exp2f(lv[r] * LOG2E) * rs;     // p(label_l)
            }
        }
        if (w == 0 && k >= 1) {
            const int kb = (k - 1) & 1;
            const int base = (k - 1) * TCH;
            float pba[8], poa[8], pbb[8], pob[8];
            #pragma unroll
            for (int j = 0; j < 8; ++j) { pba[j] = Pb[kb][j][l]; poa[j] = Po[kb][j][l]; }
            if (base == 0) {
                a0 = (l == 0) ? (double)pba[0] : 0.0;  // alpha0[0]
                a1 = (l == 0) ? (double)poa[0] : 0.0;  // alpha0[1]
                a2 = 0.0;
            }
            for (int g = 0; g < 8; ++g) {
                if (g < 7) {
                    #pragma unroll
                    for (int j = 0; j < 8; ++j) {
                        pbb[j] = Pb[kb][(g + 1) * 8 + j][l];
                        pob[j] = Po[kb][(g + 1) * 8 + j][l];
                    }
                }
                #pragma unroll
                for (int j = 0; j < 8; ++j) {
                    const int t = base + g * 8 + j;
                    if (t >= 1 && t < len) {         // wave-uniform guard
                        const double p = shr1d(a1);  // alpha[2l-1]
                        const double c = skip ? p : 0.0;
                        const double a0n = (a0 + p) * (double)pba[j];
                        const double a1n = ((a1 + a0) + c) * (double)poa[j];
                        const double a2n = (a2 + a1) * (double)pba[j];
                        a0 = a0n; a1 = a1n; a2 = a2n;
                    }
                }
                if (g == 3 || g == 7) rescale(a0, a1, a2, scale_total);
                if (g < 7) {
                    #pragma unroll
                    for (int j = 0; j < 8; ++j) { pba[j] = pbb[j]; poa[j] = pob[j]; }
                }
            }
        }
        __syncthreads();
    }

    if (w == 0) {
        alpha_sh[2 * l]     = log2_pos(a0);
        alpha_sh[2 * l + 1] = log2_pos(a1);
        if (l == 63) alpha_sh[128] = log2_pos(a2);
    }
    __syncthreads();
    if (threadIdx.x == 0) {
        const int tl = tg_len[b];
        const float al = alpha_sh[2 * tl];
        const float ap = alpha_sh[2 * tl - 1];
        const float m  = fmaxf(al, ap);
        const float lse2 = m + __log2f(exp2f(al - m) + exp2f(ap - m));
        float loss = -LN2 * (lse2 + (float)scale_total);
        if (!(loss < 1e20f)) loss = 0.0f;        // zero_infinity (inf/nan -> 0)
        atomicAdd(out, loss / (float)tl * (1.0f / (float)B_));
    }
}

extern "C" void kernel_launch(void* const* d_in, const int* in_sizes, int n_in,
                              void* d_out, int out_size, void* d_ws, size_t ws_size,
                              hipStream_t stream) {
    const float* logits  = (const float*)d_in[0];
    const int*   targets = (const int*)d_in[1];
    const int*   in_len  = (const int*)d_in[2];
    const int*   tg_len  = (const int*)d_in[3];
    float*       out     = (float*)d_out;

    (void)hipMemsetAsync(d_out, 0, sizeof(float), stream);
    k_fused<<<B_, 576, 0, stream>>>(logits, targets, in_len, tg_len, out);
}

// Round 8
// 203.542 us; speedup vs baseline: 1.1329x; 1.0033x over previous
//
#include <hip/hip_runtime.h>

#define B_ 256
#define T_ 512
#define C_ 256
#define L_ 64
#define S_ 129
#define TCH 64      // timesteps per pipelined chunk (T_/TCH = 8 chunks)
#define LOG2E 1.44269504f
#define LN2 0.69314718f

template <int CTRL>
__device__ __forceinline__ int dpp_mov_i32(int x) {
    return __builtin_amdgcn_update_dpp(0, x, CTRL, 0xF, 0xF, true);
}

// f64 whole-wave shift-right-by-1 (lane l <- lane l-1; lane 0 <- +0.0).
__device__ __forceinline__ double shr1d(double x) {
    int2 u = __builtin_bit_cast(int2, x);
    u.x = dpp_mov_i32<0x138>(u.x);
    u.y = dpp_mov_i32<0x138>(u.y);
    return __builtin_bit_cast(double, u);
}

template <int CTRL>
__device__ __forceinline__ double dpp_mov_f64(double x) {
    int2 u = __builtin_bit_cast(int2, x);
    u.x = dpp_mov_i32<CTRL>(u.x);
    u.y = dpp_mov_i32<CTRL>(u.y);
    return __builtin_bit_cast(double, u);
}

// wave64 f32 sum on the VALU; total lands in lane 63, broadcast via readlane.
__device__ __forceinline__ float wave_sum(float x) {
#define DPPADD(ctrl)                                                          \
    x += __builtin_bit_cast(float, dpp_mov_i32<ctrl>(__builtin_bit_cast(int, x)));
    DPPADD(0x111) DPPADD(0x112) DPPADD(0x114)
    DPPADD(0x118) DPPADD(0x142) DPPADD(0x143)
#undef DPPADD
    return __builtin_bit_cast(float,
        __builtin_amdgcn_readlane(__builtin_bit_cast(int, x), 63));
}

// wave64 max of nonneg doubles, broadcast to all lanes.
__device__ __forceinline__ double wave_max_d(double x) {
    x = fmax(x, dpp_mov_f64<0x111>(x));
    x = fmax(x, dpp_mov_f64<0x112>(x));
    x = fmax(x, dpp_mov_f64<0x114>(x));
    x = fmax(x, dpp_mov_f64<0x118>(x));
    x = fmax(x, dpp_mov_f64<0x142>(x));
    x = fmax(x, dpp_mov_f64<0x143>(x));
    int2 u = __builtin_bit_cast(int2, x);
    u.x = __builtin_amdgcn_readlane(u.x, 63);
    u.y = __builtin_amdgcn_readlane(u.y, 63);
    return __builtin_bit_cast(double, u);
}

// Exact wave-wide power-of-2 rescale; accumulated exponent in e.
__device__ __forceinline__ void rescale(double& a0, double& a1, double& a2, int& e) {
    const double m = wave_max_d(fmax(fmax(a0, a1), a2));
    const int hi = __builtin_bit_cast(int2, m).y;
    int ex = ((hi >> 20) & 0x7ff) - 1023;
    if (m == 0.0) ex = 0;                 // safety (state 0 is always > 0)
    e += ex;
    int2 fb; fb.x = 0; fb.y = (1023 - ex) << 20;
    const double f = __builtin_bit_cast(double, fb);  // exact 2^-ex
    a0 *= f; a1 *= f; a2 *= f;
}

// log2 of a positive double as float: exponent + log2(mantissa).
__device__ __forceinline__ float log2_pos(double a) {
    if (a == 0.0) return -1e30f;
    int2 u = __builtin_bit_cast(int2, a);
    const int ex = ((u.y >> 20) & 0x7ff) - 1023;
    u.y = (u.y & 0x800FFFFF) | (1023 << 20);          // mantissa in [1,2)
    const float mf = (float)__builtin_bit_cast(double, u);
    return __log2f(mf) + (float)ex;
}

// ---------------------------------------------------------------------------
// Fused kernel: one block per batch row, 9 waves.
// Waves 1..8 (producers): softmax in prob domain; chunk k+1's global loads
//   are issued BEFORE chunk k's compute (double-buffer) so VMEM stays busy
//   across the compute phase and the barrier. Label gather is done from a
//   per-wave LDS row scratch (no duplicate global fetch).
// Wave 0 (consumer): fp64 prob-domain alpha recurrence — per step only
//   shr1 + cndmask + add + mul on the serial chain; exact wave-wide 2^-e
//   rescale every 32 steps.
// ---------------------------------------------------------------------------
__global__ __launch_bounds__(576) void k_fused(const float* __restrict__ logits,
                                               const int* __restrict__ targets,
                                               const int* __restrict__ in_len,
                                               const int* __restrict__ tg_len,
                                               float* __restrict__ out) {
    const int b = blockIdx.x;
    const int w = threadIdx.x >> 6;      // 0..8
    const int l = threadIdx.x & 63;

    __shared__ float2 P[2][TCH][64];     // (p_blank, p_odd) per (t,lane) 64 KB
    __shared__ float4 rb4[8][2][64];     // per-producer-wave row scratch 16 KB
    __shared__ int   tgt_sh[L_];
    __shared__ float alpha_sh[S_];

    if (threadIdx.x < L_) tgt_sh[threadIdx.x] = targets[(b << 6) + threadIdx.x];
    __syncthreads();

    const int len = in_len[b];
    double a0 = 0.0, a1 = 0.0, a2 = 0.0;
    int scale_total = 0;                 // wave-uniform (wave 0)
    bool skip = false;
    if (w == 0) {
        const int tc = tgt_sh[l];
        const int tp = __shfl_up(tc, 1);
        skip = (l >= 1) && (tc != tp);
        __builtin_amdgcn_s_setprio(1);   // consumer owns the serial chain
    }
    const int mytgt = tgt_sh[l];

    const size_t rowbase = (size_t)b * T_;

    // producer prologue: chunk 0 loads in flight before the loop
    float4 va[8];
    if (w > 0) {
        const int tt0 = (w - 1) * 8;
        #pragma unroll
        for (int r = 0; r < 8; ++r)
            va[r] = ((const float4*)logits)[(rowbase + tt0 + r) * 64 + l];
    }

    for (int k = 0; k < 9; ++k) {
        if (w > 0 && k < 8) {
            const int tt0 = (w - 1) * 8;
            float4 vb[8];
            if (k < 7) {                 // prefetch chunk k+1 first
                #pragma unroll
                for (int r = 0; r < 8; ++r) {
                    const int t = (k + 1) * TCH + tt0 + r;
                    vb[r] = ((const float4*)logits)[(rowbase + t) * 64 + l];
                }
            }
            #pragma unroll
            for (int r = 0; r < 8; ++r) {
                const int tt = tt0 + r;
                float4 e;
                e.x = exp2f(va[r].x * LOG2E);
                e.y = exp2f(va[r].y * LOG2E);
                e.z = exp2f(va[r].z * LOG2E);
                e.w = exp2f(va[r].w * LOG2E);
                rb4[w - 1][r & 1][l] = e;             // stage exps for gather
                const float stot = wave_sum(e.x + e.y + e.z + e.w);
                const float rs = __builtin_amdgcn_rcpf(stot);
                const float eb = __builtin_bit_cast(float,
                    __builtin_amdgcn_readfirstlane(__builtin_bit_cast(int, e.x)));
                const float eo = ((const float*)&rb4[w - 1][r & 1][0])[mytgt];
                float2 pq; pq.x = eb * rs; pq.y = eo * rs;
                P[k & 1][tt][l] = pq;
            }
            #pragma unroll
            for (int r = 0; r < 8; ++r) va[r] = vb[r];
        }
        if (w == 0 && k >= 1) {
            const int kb = (k - 1) & 1;
            const int base = (k - 1) * TCH;
            float2 pa[8], pn[8];
            #pragma unroll
            for (int j = 0; j < 8; ++j) pa[j] = P[kb][j][l];
            if (base == 0) {
                a0 = (l == 0) ? (double)pa[0].x : 0.0;  // alpha0[0]
                a1 = (l == 0) ? (double)pa[0].y : 0.0;  // alpha0[1]
                a2 = 0.0;
            }
            for (int g = 0; g < 8; ++g) {
                if (g < 7) {
                    #pragma unroll
                    for (int j = 0; j < 8; ++j) pn[j] = P[kb][(g + 1) * 8 + j][l];
                }
                #pragma unroll
                for (int j = 0; j < 8; ++j) {
                    const int t = base + g * 8 + j;
                    if (t >= 1 && t < len) {         // wave-uniform guard
                        const double p = shr1d(a1);  // alpha[2l-1]
                        const double c = skip ? p : 0.0;
                        const double a0n = (a0 + p) * (double)pa[j].x;
                        const double a1n = ((a1 + a0) + c) * (double)pa[j].y;
                        const double a2n = (a2 + a1) * (double)pa[j].x;
                        a0 = a0n; a1 = a1n; a2 = a2n;
                    }
                }
                if (g == 3 || g == 7) rescale(a0, a1, a2, scale_total);
                if (g < 7) {
                    #pragma unroll
                    for (int j = 0; j < 8; ++j) pa[j] = pn[j];
                }
            }
        }
        __syncthreads();
    }

    if (w == 0) {
        alpha_sh[2 * l]     = log2_pos(a0);
        alpha_sh[2 * l + 1] = log2_pos(a1);
        if (l == 63) alpha_sh[128] = log2_pos(a2);
    }
    __syncthreads();
    if (threadIdx.x == 0) {
        const int tl = tg_len[b];
        const float al = alpha_sh[2 * tl];
        const float ap = alpha_sh[2 * tl - 1];
        const float m  = fmaxf(al, ap);
        const float lse2 = m + __log2f(exp2f(al - m) + exp2f(ap - m));
        float loss = -LN2 * (lse2 + (float)scale_total);
        if (!(loss < 1e20f)) loss = 0.0f;        // zero_infinity (inf/nan -> 0)
        atomicAdd(out, loss / (float)tl * (1.0f / (float)B_));
    }
}

extern "C" void kernel_launch(void* const* d_in, const int* in_sizes, int n_in,
                              void* d_out, int out_size, void* d_ws, size_t ws_size,
                              hipStream_t stream) {
    const float* logits  = (const float*)d_in[0];
    const int*   targets = (const int*)d_in[1];
    const int*   in_len  = (const int*)d_in[2];
    const int*   tg_len  = (const int*)d_in[3];
    float*       out     = (float*)d_out;

    (void)hipMemsetAsync(d_out, 0, sizeof(float), stream);
    k_fused<<<B_, 576, 0, stream>>>(logits, targets, in_len, tg_len, out);
}